// Round 3
// baseline (364.301 us; speedup 1.0000x reference)
//
#include <hip/hip_runtime.h>

#define WS 9
#define PS 7
#define KMAX 10
#define STRIDE0 4
#define NEPOCHS 100
#define BB 1
#define TT 5
#define CC 3
#define HH 256
#define WW 256
#define NH 64
#define NW 64
#define QQ (TT * NH * NW)             // 20480
#define NOFF 243
#define SELF_IDX 40                   // (WS/2)*WS + WS/2
#define TP 20                         // tile col padding (bank-friendly: 20 ≡ no mod-8 row alias)
#define QP 8                          // qpat/dpat row padding (b128-aligned rows)
#define DP 244                        // dpart row stride ([i][n], consecutive-n reads conflict-free)
#define NU 189                        // phase-A units: 3 dti * 9 dh * 7 i

static __device__ __forceinline__ int k_eff_from_epoch(int ep) {
    int k = (int)((double)KMAX * ((double)(NEPOCHS - ep) / (double)NEPOCHS));
    return k < 2 ? 2 : k;
}

__global__ __launch_bounds__(256) void dnls_query_kernel(
    const float* __restrict__ noisy, const float* __restrict__ deno,
    const float* __restrict__ fflow, const float* __restrict__ bflow,
    const int* __restrict__ ep_ptr, float* __restrict__ partial)
{
    const int q   = blockIdx.x;
    const int b   = q / QQ;
    const int qq  = q % QQ;
    const int tqi = qq / (NH * NW);
    const int r0  = qq % (NH * NW);
    const int hq  = (r0 / NW) * STRIDE0;
    const int wq  = (r0 % NW) * STRIDE0;
    const int tid = threadIdx.x;
    const int lane = tid & 63;
    const int HW  = HH * WW;
    const int k_eff = k_eff_from_epoch(ep_ptr[0]);

    __shared__ float tile[3][CC][15][TP];   // union search windows (noisy), row-padded
    __shared__ float qpat[CC][PS][QP];      // noisy query patch
    __shared__ float dpat[CC][PS][QP];      // deno query patch
    __shared__ float dpart[PS][DP];         // per-patch-row partial distances, [i][n]
    __shared__ int   tcenS[3], hcenS[3], wcenS[3], h0S[3], w0S[3];
    __shared__ float redbuf[4];

    // --- centers from rounded flow at the query location ---
    if (tid == 0) {
        const size_t bf = ((size_t)(b * TT + tqi) * 2) * HW + (size_t)hq * WW + wq;
        const int ifdx = (int)rintf(fflow[bf]);
        const int ifdy = (int)rintf(fflow[bf + HW]);
        const int ibdx = (int)rintf(bflow[bf]);
        const int ibdy = (int)rintf(bflow[bf + HW]);
        tcenS[0] = tqi; tcenS[1] = max(tqi - 1, 0); tcenS[2] = min(tqi + 1, TT - 1);
        hcenS[0] = hq;
        hcenS[1] = min(max(hq + ibdy, 0), HH - 1);
        hcenS[2] = min(max(hq + ifdy, 0), HH - 1);
        wcenS[0] = wq;
        wcenS[1] = min(max(wq + ibdx, 0), WW - 1);
        wcenS[2] = min(max(wq + ifdx, 0), WW - 1);
        #pragma unroll
        for (int d = 0; d < 3; ++d) {
            h0S[d] = max(hcenS[d] - 4, 0);
            w0S[d] = max(wcenS[d] - 4, 0);
        }
    }
    __syncthreads();

    // --- stage the 3 union windows into padded LDS tiles (pad cols load dup data) ---
    for (int p = tid; p < 3 * CC * 15 * TP; p += 256) {
        const int dti = p / (CC * 15 * TP);
        const int r1  = p - dti * (CC * 15 * TP);
        const int c   = r1 / (15 * TP);
        const int r2  = r1 - c * (15 * TP);
        const int row = r2 / TP;
        const int col = r2 - row * TP;
        const int hh  = min(h0S[dti] + row, HH - 1);
        const int ww  = min(w0S[dti] + min(col, 14), WW - 1);
        tile[dti][c][row][col] =
            noisy[(size_t)((b * TT + tcenS[dti]) * CC + c) * HW + hh * WW + ww];
    }
    if (tid < CC * PS * PS) {
        const int c = tid / 49, ij = tid % 49, i = ij / 7, j = ij % 7;
        const int hh = min(hq + i, HH - 1), ww = min(wq + j, WW - 1);
        const size_t idx = (size_t)((b * TT + tqi) * CC + c) * HW + hh * WW + ww;
        qpat[c][i][j] = noisy[idx];
        dpat[c][i][j] = deno[idx];
    }
    __syncthreads();

    // --- phase A: sliding-window row correlation; unit = (dh, dti, i) ---
    if (tid < NU) {
        const int dh  = tid / 21;
        const int rem = tid - dh * 21;
        const int dti = rem / 7;
        const int i   = rem - dti * 7;
        const int hcen_ = hcenS[dti], wcen_ = wcenS[dti];
        const int h0_ = h0S[dti], w0_ = w0S[dti];
        const int r = min(min(max(hcen_ + dh - 4, 0), HH - 1) + i, HH - 1) - h0_;
        float acc[9];
        #pragma unroll
        for (int d = 0; d < 9; ++d) acc[d] = 0.f;

        const bool fastw = (wcen_ >= 4) && (wcen_ <= WW - 11);  // cols = dw+j, no clamps
        if (fastw) {
            #pragma unroll
            for (int c = 0; c < CC; ++c) {
                float qv[8];
                *(float4*)&qv[0] = *(const float4*)&qpat[c][i][0];
                *(float4*)&qv[4] = *(const float4*)&qpat[c][i][4];
                float tv[16];
                *(float4*)&tv[0]  = *(const float4*)&tile[dti][c][r][0];
                *(float4*)&tv[4]  = *(const float4*)&tile[dti][c][r][4];
                *(float4*)&tv[8]  = *(const float4*)&tile[dti][c][r][8];
                *(float4*)&tv[12] = *(const float4*)&tile[dti][c][r][12];
                #pragma unroll
                for (int dw = 0; dw < 9; ++dw) {
                    #pragma unroll
                    for (int j = 0; j < 7; ++j) {
                        const float d = qv[j] - tv[dw + j];
                        acc[dw] = fmaf(d, d, acc[dw]);
                    }
                }
            }
        } else {
            const int wcm4 = wcen_ - 4;
            #pragma unroll
            for (int c = 0; c < CC; ++c) {
                float qv[8];
                *(float4*)&qv[0] = *(const float4*)&qpat[c][i][0];
                *(float4*)&qv[4] = *(const float4*)&qpat[c][i][4];
                #pragma unroll
                for (int dw = 0; dw < 9; ++dw) {
                    const int wc = min(max(wcm4 + dw, 0), WW - 1);
                    #pragma unroll
                    for (int j = 0; j < 7; ++j) {
                        const int col = min(wc + j, WW - 1) - w0_;
                        const float d = qv[j] - tile[dti][c][r][col];
                        acc[dw] = fmaf(d, d, acc[dw]);
                    }
                }
            }
        }
        const int n0 = dti * 81 + dh * 9;
        #pragma unroll
        for (int dw = 0; dw < 9; ++dw) dpart[i][n0 + dw] = acc[dw];
    }
    __syncthreads();

    // --- phase B: per-lane candidate sums + fully in-register per-wave top-k ---
    float dv[4]; int dn[4];
    #pragma unroll
    for (int kk = 0; kk < 4; ++kk) {
        const int n = lane + kk * 64;
        float s = INFINITY;
        if (n < NOFF) {
            float t = 0.f;
            #pragma unroll
            for (int i = 0; i < PS; ++i) t += dpart[i][n];
            s = (n == SELF_IDX) ? -INFINITY : t;   // anchor self to slot 0
        }
        dv[kk] = s; dn[kk] = n;
    }
    int seln[KMAX];
    #pragma unroll
    for (int k = 0; k < KMAX; ++k) {
        float bv = dv[0]; int bi = dn[0];
        #pragma unroll
        for (int kk = 1; kk < 4; ++kk)
            if (dv[kk] < bv || (dv[kk] == bv && dn[kk] < bi)) { bv = dv[kk]; bi = dn[kk]; }
        #pragma unroll
        for (int off = 32; off > 0; off >>= 1) {
            const float ov = __shfl_xor(bv, off);
            const int   oi = __shfl_xor(bi, off);
            if (ov < bv || (ov == bv && oi < bi)) { bv = ov; bi = oi; }
        }
        seln[k] = bi;                              // same in all lanes
        #pragma unroll
        for (int kk = 0; kk < 4; ++kk) if (dn[kk] == bi) dv[kk] = INFINITY;
    }

    // --- refine: deno-query vs noisy at selected positions (slots 1..k_eff-1) ---
    float part = 0.f;
    const int nref = (k_eff - 1) * 49;
    for (int u = tid; u < nref; u += 256) {
        const int kk = u / 49 + 1;
        const int ij = u - (kk - 1) * 49;
        const int i = ij / 7, j = ij - (ij / 7) * 7;
        int n = seln[1];
        #pragma unroll
        for (int t = 2; t < KMAX; ++t) if (kk == t) n = seln[t];  // constant-indexed select
        const int dti = n / 81;
        const int rr  = n - dti * 81;
        const int dh  = rr / 9;
        const int dw  = rr - dh * 9;
        const int hc  = min(max(hcenS[dti] + dh - 4, 0), HH - 1);
        const int wc  = min(max(wcenS[dti] + dw - 4, 0), WW - 1);
        const int row = min(hc + i, HH - 1) - h0S[dti];
        const int col = min(wc + j, WW - 1) - w0S[dti];
        #pragma unroll
        for (int c = 0; c < CC; ++c) {
            const float d = dpat[c][i][j] - tile[dti][c][row][col];
            part = fmaf(d, d, part);
        }
    }

    // --- block reduce: wave butterfly + 4-slot LDS ---
    #pragma unroll
    for (int off = 32; off > 0; off >>= 1) part += __shfl_xor(part, off);
    if (lane == 0) redbuf[tid >> 6] = part;
    __syncthreads();
    if (tid == 0) partial[q] = redbuf[0] + redbuf[1] + redbuf[2] + redbuf[3];
}

__global__ __launch_bounds__(1024) void dnls_reduce_kernel(
    const float* __restrict__ partial, int n,
    const int* __restrict__ ep_ptr, float* __restrict__ out)
{
    const int tid = threadIdx.x;
    double acc = 0.0;
    for (int i = tid; i < n; i += 1024) acc += (double)partial[i];
    __shared__ double red[1024];
    red[tid] = acc;
    __syncthreads();
    for (int s = 512; s > 0; s >>= 1) {
        if (tid < s) red[tid] += red[tid + s];
        __syncthreads();
    }
    if (tid == 0) {
        const int k_eff = k_eff_from_epoch(ep_ptr[0]);
        out[0] = (float)(red[0] / ((double)n * (double)(k_eff - 1)));
    }
}

extern "C" void kernel_launch(void* const* d_in, const int* in_sizes, int n_in,
                              void* d_out, int out_size, void* d_ws, size_t ws_size,
                              hipStream_t stream) {
    const float* noisy = (const float*)d_in[0];
    const float* deno  = (const float*)d_in[1];
    const float* fflow = (const float*)d_in[2];
    const float* bflow = (const float*)d_in[3];
    const int*   ep    = (const int*)d_in[4];
    float* partial = (float*)d_ws;            // BB*QQ floats = 80 KB
    float* out = (float*)d_out;

    dnls_query_kernel<<<BB * QQ, 256, 0, stream>>>(noisy, deno, fflow, bflow, ep, partial);
    dnls_reduce_kernel<<<1, 1024, 0, stream>>>(partial, BB * QQ, ep, out);
}